// Round 11
// baseline (52.739 us; speedup 1.0000x reference)
//
#include <hip/hip_runtime.h>
#include <hip/hip_bf16.h>

#define NB 4
#define NN 2048
#define KK 32
#define DD 64
#define R2C 0.64f

typedef __attribute__((ext_vector_type(8)))  short short8;   // 8 bf16 (4 VGPRs)
typedef __attribute__((ext_vector_type(16))) float f32x16;   // 32x32 MFMA acc
typedef __attribute__((ext_vector_type(4)))  int   i32x4;

__device__ __forceinline__ unsigned short f2bf(float f) {
    __hip_bfloat16 h = __float2bfloat16(f);
    return reinterpret_cast<unsigned short&>(h);
}
__device__ __forceinline__ int cvtpk(float lo, float hi) {
    int r;
    asm("v_cvt_pk_bf16_f32 %0, %1, %2" : "=v"(r) : "v"(lo), "v"(hi));
    return r;
}
__device__ __forceinline__ int pkmax(int a, int b) {   // per-16-bit signed max (valid for bf16>=0)
    int r;
    asm("v_pk_max_i16 %0, %1, %2" : "=v"(r) : "v"(a), "v"(b));
    return r;
}
__device__ __forceinline__ short8 fr(const int* d) {
    i32x4 v = { d[0], d[1], d[2], d[3] };
    return __builtin_bit_cast(short8, v);
}
__device__ __forceinline__ float sel16(const f32x16& a, int s) {  // static-unrolled select
    float r = a[0];
#pragma unroll
    for (int i = 1; i < 16; ++i) r = (s == i) ? a[i] : r;
    return r;
}
// gather 8 consecutive f32 -> bf16 short8 fragment (RNE)
__device__ __forceinline__ short8 cvt8(const float* __restrict__ p) {
    float4 a = ((const float4*)p)[0];
    float4 b = ((const float4*)p)[1];
    short8 r;
    r[0] = (short)f2bf(a.x); r[1] = (short)f2bf(a.y); r[2] = (short)f2bf(a.z); r[3] = (short)f2bf(a.w);
    r[4] = (short)f2bf(b.x); r[5] = (short)f2bf(b.y); r[6] = (short)f2bf(b.z); r[7] = (short)f2bf(b.w);
    return r;
}

#define MF(A, B, C) __builtin_amdgcn_mfma_f32_32x32x16_bf16(A, B, C, 0, 0, 0)

__global__ __launch_bounds__(256, 2) void fused_kernel(const float* __restrict__ x,
                                                       const float* __restrict__ pos,
                                                       const float* __restrict__ Wf,
                                                       const float* __restrict__ bfv,
                                                       const float* __restrict__ W1,
                                                       const float* __restrict__ b1,
                                                       const float* __restrict__ W2,
                                                       const float* __restrict__ b2,
                                                       const float* __restrict__ Wl,
                                                       const float* __restrict__ bl,
                                                       float* __restrict__ out) {
    __shared__ short8 lwf8[16 * 64];          // 16 KB A-fragments (weights)
    __shared__ int nbrs[4][4][KK];            // 2 KB
    __shared__ float bss[4][4 * 128];         // 8 KB per-query bases
    int wid = threadIdx.x >> 6, lane = threadIdx.x & 63;
    int qp = __builtin_amdgcn_readfirstlane(blockIdx.x * 4 + wid);
    int q0 = qp << 2;                         // 4 queries per wave, same batch
    int col = lane & 31, g = lane >> 5;
    int b = q0 >> 11, n0 = q0 & (NN - 1);

    // ---- A-fragment build: lane row = out-channel, slot k = in-channel ----
    // f0-3: w0k natural k-labels. f4-15: pi-permuted so prev layer's D-register
    // form IS the next B-fragment: slot(g2,j,fl) must hold in-ch (j&3)+8*(j>>2)+16fl+4g2.
    for (int e = threadIdx.x; e < 1024; e += 256) {
        int f = e >> 6, l = e & 63;
        int c = l & 31, g2 = l >> 5;
        unsigned short u[8];
#pragma unroll
        for (int j = 0; j < 8; ++j) {
            float v;
            if (f < 4) {
                int rr = 16 * f + 8 * g2 + j;
                v = Wf[(64 + rr) * 32 + c] + Wf[(128 + rr) * 32 + c];
            } else {
                int fl = f & 1;
                int rr = 4 * g2 + (j & 3) + 8 * ((j >> 2) + 2 * fl);
                if (f < 6)       v = W1[rr * 32 + c];
                else if (f < 8)  v = W2[rr * 32 + c];
                else if (f < 10) v = W2[(32 + rr) * 32 + c];
                else if (f < 12) v = Wl[rr * 32 + c];
                else if (f < 14) v = Wl[(32 + rr) * 32 + c];
                else             v = Wl[(64 + rr) * 32 + c];
            }
            u[j] = f2bf(v);
        }
        i32x4 pk = { (int)(u[0] | (u[1] << 16)), (int)(u[2] | (u[3] << 16)),
                     (int)(u[4] | (u[5] << 16)), (int)(u[6] | (u[7] << 16)) };
        lwf8[e] = __builtin_bit_cast(short8, pk);
    }

    // ---- bases from RAW weights (coalesced per half-wave), 8 independent FMA chains ----
    const float* xq0 = x + (size_t)q0 * DD;
    bool lo = lane < 32;
    int c0 = lane & 31;
    const float* pA1 = lo ? (Wf + c0) : (W1 + 32 * 32 + c0);
    const float* pA2 = lo ? (Wf + 128 * 32 + c0) : (W1 + 32 * 32 + c0);
    float sA = lo ? -1.0f : 0.0f;
    const float* pB1 = lo ? (W2 + 64 * 32 + c0) : (Wl + 96 * 32 + c0);
    float balA = lo ? bfv[c0] : b1[c0];
    float balB = lo ? b2[c0] : bl[c0];
    float aA[4] = {balA, balA, balA, balA};
    float aB[4] = {balB, balB, balB, balB};
#pragma unroll
    for (int j0 = 0; j0 < 16; ++j0) {
        float wa[4], wb[4];
#pragma unroll
        for (int jj = 0; jj < 4; ++jj) {
            int j = 4 * j0 + jj;
            wa[jj] = fmaf(sA, pA2[j * 32], pA1[j * 32]);
            wb[jj] = pB1[j * 32];
        }
#pragma unroll
        for (int t = 0; t < 4; ++t) {
            const float* xr = xq0 + t * DD + 4 * j0;
            float x0 = xr[0], x1 = xr[1], x2 = xr[2], x3 = xr[3];
            aA[t] = fmaf(x0, wa[0], aA[t]); aA[t] = fmaf(x1, wa[1], aA[t]);
            aA[t] = fmaf(x2, wa[2], aA[t]); aA[t] = fmaf(x3, wa[3], aA[t]);
            aB[t] = fmaf(x0, wb[0], aB[t]); aB[t] = fmaf(x1, wb[1], aB[t]);
            aB[t] = fmaf(x2, wb[2], aB[t]); aB[t] = fmaf(x3, wb[3], aB[t]);
        }
    }
#pragma unroll
    for (int t = 0; t < 4; ++t) {
        bss[wid][t * 128 + lane]      = aA[t];   // L0 (lo lanes) / L1 (hi lanes)
        bss[wid][t * 128 + 64 + lane] = aB[t];   // L2 / L3
    }

    // ---- shared-chunk ball query (exact reference arithmetic) ----
    const float* pb = pos + (size_t)b * NN * 3;
    float qxv[4], qyv[4], qzv[4], sq4[4];
#pragma unroll
    for (int t = 0; t < 4; ++t) {
        int n = n0 + t;
        qxv[t] = pb[3 * n]; qyv[t] = pb[3 * n + 1]; qzv[t] = pb[3 * n + 2];
        sq4[t] = __fadd_rn(__fadd_rn(__fmul_rn(qxv[t], qxv[t]), __fmul_rn(qyv[t], qyv[t])),
                           __fmul_rn(qzv[t], qzv[t]));
    }
    int cnt[4] = {0, 0, 0, 0};
    unsigned long long ltmask = (1ULL << lane) - 1ULL;
    for (int m0 = 0; m0 < NN; m0 += 64) {
        if (cnt[0] >= KK && cnt[1] >= KK && cnt[2] >= KK && cnt[3] >= KK) break;
        int m = m0 + lane;
        float mx3 = pb[3 * m], my3 = pb[3 * m + 1], mz3 = pb[3 * m + 2];
        float sqm = __fadd_rn(__fadd_rn(__fmul_rn(mx3, mx3), __fmul_rn(my3, my3)), __fmul_rn(mz3, mz3));
#pragma unroll
        for (int t = 0; t < 4; ++t) {
            if (cnt[t] < KK) {
                float dot = __fadd_rn(__fadd_rn(__fmul_rn(qxv[t], mx3), __fmul_rn(qyv[t], my3)),
                                      __fmul_rn(qzv[t], mz3));
                float d2 = __fsub_rn(__fadd_rn(sq4[t], sqm), __fmul_rn(2.0f, dot));
                bool hit = d2 < R2C;
                unsigned long long mask = __ballot(hit);
                if (hit) {
                    int p = cnt[t] + (int)__popcll(mask & ltmask);
                    if (p < KK) nbrs[wid][t][p] = m;
                }
                cnt[t] = __builtin_amdgcn_readfirstlane(cnt[t] + (int)__popcll(mask));
            }
        }
    }
    int nbn[4];
#pragma unroll
    for (int t = 0; t < 4; ++t) nbn[t] = nbrs[wid][t][col < cnt[t] ? col : 0];

    // ---- gather neighbor rows (B-frags: lane col = neighbor, slots = features) ----
    short8 xk[4][4];
#pragma unroll
    for (int t = 0; t < 4; ++t) {
        const float* xrow = x + (size_t)(b * NN + nbn[t]) * DD + g * 8;
#pragma unroll
        for (int kf = 0; kf < 4; ++kf) xk[t][kf] = cvt8(xrow + kf * 16);
    }

    __syncthreads();     // lwf8 ready
    const float* bp = bss[wid];

    auto bias_init = [&](f32x16& acc, int t, int L) {
#pragma unroll
        for (int m = 0; m < 4; ++m) {
            float4 r = *(const float4*)(bp + t * 128 + L * 32 + 8 * m + 4 * g);
            acc[4 * m] = r.x; acc[4 * m + 1] = r.y; acc[4 * m + 2] = r.z; acc[4 * m + 3] = r.w;
        }
    };
    auto post_pack = [&](const f32x16& a, int* d) {      // relu + pack: D-form -> next B-frag dwords
#pragma unroll
        for (int i = 0; i < 8; ++i)
            d[i] = cvtpk(fmaxf(a[2 * i], 0.0f), fmaxf(a[2 * i + 1], 0.0f));
    };
    // max over neighbors for packed non-negative bf16 (relu layers) -> out
    auto maxstore_pk = [&](int* d, float* orow, int off) {
#pragma unroll
        for (int ms = 1; ms < 32; ms <<= 1) {
#pragma unroll
            for (int i = 0; i < 8; ++i) d[i] = pkmax(d[i], __shfl_xor(d[i], ms, 32));
        }
        int s = lane & 7;
        int sel = s == 0 ? d[0] : s == 1 ? d[1] : s == 2 ? d[2] : s == 3 ? d[3]
                : s == 4 ? d[4] : s == 5 ? d[5] : s == 6 ? d[6] : d[7];
        if (col < 8) {
            int c = ((2 * s) & 3) + 8 * (s >> 1) + 4 * g;
            float2 v = make_float2(__int_as_float(sel << 16),
                                   __int_as_float(sel & (int)0xFFFF0000));
            *(float2*)(orow + off + c) = v;
        }
    };
    // f32 max over neighbors for L3 (signed values; no packed trick)
    auto maxstore_f32 = [&](f32x16& a, float* orow) {
#pragma unroll
        for (int ms = 1; ms < 32; ms <<= 1) {
#pragma unroll
            for (int p = 0; p < 16; ++p) a[p] = fmaxf(a[p], __shfl_xor(a[p], ms, 32));
        }
        if (col < 8) {
            int c = ((2 * col) & 3) + 8 * (col >> 1) + 4 * g;
            float v0 = sel16(a, 2 * col);
            float v1 = sel16(a, 2 * col + 1);
            *(float2*)(orow + c) = make_float2(v0, v1);
        }
    };

#define WLD(f) lwf8[(f) * 64 + lane]
    f32x16 a0, a1, a2, a3;
    int h0d[4][8], h1d[4][8], h2d[4][8];

    // ---- L0: acc = bias + (w0k)^T . X^T ----
    bias_init(a0, 0, 0); bias_init(a1, 1, 0); bias_init(a2, 2, 0); bias_init(a3, 3, 0);
    a0 = MF(WLD(0), xk[0][0], a0); a0 = MF(WLD(1), xk[0][1], a0);
    a0 = MF(WLD(2), xk[0][2], a0); a0 = MF(WLD(3), xk[0][3], a0);
    a1 = MF(WLD(0), xk[1][0], a1); a1 = MF(WLD(1), xk[1][1], a1);
    a1 = MF(WLD(2), xk[1][2], a1); a1 = MF(WLD(3), xk[1][3], a1);
    post_pack(a0, h0d[0]);
    a2 = MF(WLD(0), xk[2][0], a2); a2 = MF(WLD(1), xk[2][1], a2);
    a2 = MF(WLD(2), xk[2][2], a2); a2 = MF(WLD(3), xk[2][3], a2);
    post_pack(a1, h0d[1]);
    a3 = MF(WLD(0), xk[3][0], a3); a3 = MF(WLD(1), xk[3][1], a3);
    a3 = MF(WLD(2), xk[3][2], a3); a3 = MF(WLD(3), xk[3][3], a3);
    post_pack(a2, h0d[2]);
    post_pack(a3, h0d[3]);

    // ---- L1 ----
    bias_init(a0, 0, 1); bias_init(a1, 1, 1); bias_init(a2, 2, 1); bias_init(a3, 3, 1);
    a0 = MF(WLD(4), fr(h0d[0]), a0); a0 = MF(WLD(5), fr(h0d[0] + 4), a0);
    a1 = MF(WLD(4), fr(h0d[1]), a1); a1 = MF(WLD(5), fr(h0d[1] + 4), a1);
    post_pack(a0, h1d[0]);
    a2 = MF(WLD(4), fr(h0d[2]), a2); a2 = MF(WLD(5), fr(h0d[2] + 4), a2);
    post_pack(a1, h1d[1]);
    a3 = MF(WLD(4), fr(h0d[3]), a3); a3 = MF(WLD(5), fr(h0d[3] + 4), a3);
    post_pack(a2, h1d[2]);
    post_pack(a3, h1d[3]);

    // ---- L2 ----
    bias_init(a0, 0, 2); bias_init(a1, 1, 2); bias_init(a2, 2, 2); bias_init(a3, 3, 2);
    a0 = MF(WLD(6), fr(h1d[0]), a0); a0 = MF(WLD(7), fr(h1d[0] + 4), a0);
    a0 = MF(WLD(8), fr(h0d[0]), a0); a0 = MF(WLD(9), fr(h0d[0] + 4), a0);
    a1 = MF(WLD(6), fr(h1d[1]), a1); a1 = MF(WLD(7), fr(h1d[1] + 4), a1);
    a1 = MF(WLD(8), fr(h0d[1]), a1); a1 = MF(WLD(9), fr(h0d[1] + 4), a1);
    post_pack(a0, h2d[0]);
    a2 = MF(WLD(6), fr(h1d[2]), a2); a2 = MF(WLD(7), fr(h1d[2] + 4), a2);
    a2 = MF(WLD(8), fr(h0d[2]), a2); a2 = MF(WLD(9), fr(h0d[2] + 4), a2);
    post_pack(a1, h2d[1]);
    a3 = MF(WLD(6), fr(h1d[3]), a3); a3 = MF(WLD(7), fr(h1d[3] + 4), a3);
    a3 = MF(WLD(8), fr(h0d[3]), a3); a3 = MF(WLD(9), fr(h0d[3] + 4), a3);
    post_pack(a2, h2d[2]);
    post_pack(a3, h2d[3]);

    // ---- L3 (no relu) + f32 max/store ----
    bias_init(a0, 0, 3); bias_init(a1, 1, 3); bias_init(a2, 2, 3); bias_init(a3, 3, 3);
    a0 = MF(WLD(10), fr(h2d[0]), a0); a0 = MF(WLD(11), fr(h2d[0] + 4), a0);
    a0 = MF(WLD(12), fr(h1d[0]), a0); a0 = MF(WLD(13), fr(h1d[0] + 4), a0);
    a0 = MF(WLD(14), fr(h0d[0]), a0); a0 = MF(WLD(15), fr(h0d[0] + 4), a0);
    a1 = MF(WLD(10), fr(h2d[1]), a1); a1 = MF(WLD(11), fr(h2d[1] + 4), a1);
    a1 = MF(WLD(12), fr(h1d[1]), a1); a1 = MF(WLD(13), fr(h1d[1] + 4), a1);
    a1 = MF(WLD(14), fr(h0d[1]), a1); a1 = MF(WLD(15), fr(h0d[1] + 4), a1);
    maxstore_f32(a0, out + (size_t)(q0 + 0) * 192);
    a2 = MF(WLD(10), fr(h2d[2]), a2); a2 = MF(WLD(11), fr(h2d[2] + 4), a2);
    a2 = MF(WLD(12), fr(h1d[2]), a2); a2 = MF(WLD(13), fr(h1d[2] + 4), a2);
    a2 = MF(WLD(14), fr(h0d[2]), a2); a2 = MF(WLD(15), fr(h0d[2] + 4), a2);
    maxstore_f32(a1, out + (size_t)(q0 + 1) * 192);
    a3 = MF(WLD(10), fr(h2d[3]), a3); a3 = MF(WLD(11), fr(h2d[3] + 4), a3);
    a3 = MF(WLD(12), fr(h1d[3]), a3); a3 = MF(WLD(13), fr(h1d[3] + 4), a3);
    a3 = MF(WLD(14), fr(h0d[3]), a3); a3 = MF(WLD(15), fr(h0d[3] + 4), a3);
    maxstore_f32(a2, out + (size_t)(q0 + 2) * 192);
    maxstore_f32(a3, out + (size_t)(q0 + 3) * 192);

    // ---- deferred maxes for relu layers (packed bf16 >= 0) ----
#pragma unroll
    for (int t = 0; t < 4; ++t) {
        float* o = out + (size_t)(q0 + t) * 192;
        maxstore_pk(h2d[t], o, 32);
        maxstore_pk(h1d[t], o, 64);
        maxstore_pk(h0d[t], o, 96);
        o[128 + lane] = xq0[t * DD + lane];   // x passthrough
    }
}

extern "C" void kernel_launch(void* const* d_in, const int* in_sizes, int n_in,
                              void* d_out, int out_size, void* d_ws, size_t ws_size,
                              hipStream_t stream) {
    const float* x   = (const float*)d_in[0];
    const float* pos = (const float*)d_in[1];
    const float* Wf  = (const float*)d_in[2];
    const float* bf  = (const float*)d_in[3];
    const float* W1  = (const float*)d_in[4];
    const float* b1  = (const float*)d_in[5];
    const float* W2  = (const float*)d_in[6];
    const float* b2  = (const float*)d_in[7];
    const float* Wl  = (const float*)d_in[8];
    const float* bl  = (const float*)d_in[9];
    float* out = (float*)d_out;

    hipLaunchKernelGGL(fused_kernel, dim3(512), dim3(256), 0, stream,
                       x, pos, Wf, bf, W1, b1, W2, b2, Wl, bl, out);
}

// Round 12
// 43.268 us; speedup vs baseline: 1.2189x; 1.2189x over previous
//
#include <hip/hip_runtime.h>
#include <hip/hip_bf16.h>

#define NB 4
#define NN 2048
#define KK 32
#define DD 64
#define R2C 0.64f

typedef __attribute__((ext_vector_type(8)))  short short8;   // 8 bf16 (4 VGPRs)
typedef __attribute__((ext_vector_type(16))) float f32x16;   // 32x32 MFMA acc
typedef __attribute__((ext_vector_type(4)))  int   i32x4;

__device__ __forceinline__ unsigned short f2bf(float f) {
    __hip_bfloat16 h = __float2bfloat16(f);
    return reinterpret_cast<unsigned short&>(h);
}
__device__ __forceinline__ int cvtpk(float lo, float hi) {
    int r;
    asm("v_cvt_pk_bf16_f32 %0, %1, %2" : "=v"(r) : "v"(lo), "v"(hi));
    return r;
}
__device__ __forceinline__ int pkmax(int a, int b) {   // per-16-bit signed max (valid for bf16>=0)
    int r;
    asm("v_pk_max_i16 %0, %1, %2" : "=v"(r) : "v"(a), "v"(b));
    return r;
}
__device__ __forceinline__ short8 fr(const int* d) {
    i32x4 v = { d[0], d[1], d[2], d[3] };
    return __builtin_bit_cast(short8, v);
}
__device__ __forceinline__ float sel16(const f32x16& a, int s) {  // static-unrolled select
    float r = a[0];
#pragma unroll
    for (int i = 1; i < 16; ++i) r = (s == i) ? a[i] : r;
    return r;
}
// gather 8 consecutive f32 -> bf16 short8 fragment (RNE)
__device__ __forceinline__ short8 cvt8(const float* __restrict__ p) {
    float4 a = ((const float4*)p)[0];
    float4 b = ((const float4*)p)[1];
    short8 r;
    r[0] = (short)f2bf(a.x); r[1] = (short)f2bf(a.y); r[2] = (short)f2bf(a.z); r[3] = (short)f2bf(a.w);
    r[4] = (short)f2bf(b.x); r[5] = (short)f2bf(b.y); r[6] = (short)f2bf(b.z); r[7] = (short)f2bf(b.w);
    return r;
}

#define MF(A, B, C) __builtin_amdgcn_mfma_f32_32x32x16_bf16(A, B, C, 0, 0, 0)

__global__ __launch_bounds__(256, 2) void fused_kernel(const float* __restrict__ x,
                                                       const float* __restrict__ pos,
                                                       const float* __restrict__ Wf,
                                                       const float* __restrict__ bfv,
                                                       const float* __restrict__ W1,
                                                       const float* __restrict__ b1,
                                                       const float* __restrict__ W2,
                                                       const float* __restrict__ b2,
                                                       const float* __restrict__ Wl,
                                                       const float* __restrict__ bl,
                                                       float* __restrict__ out) {
    __shared__ short8 lwf8[16 * 64];          // 16 KB A-fragments (weights)
    __shared__ int nbrs[4][4][KK];            // 2 KB
    __shared__ float bss[4][4 * 128];         // 8 KB per-query bases
    int wid = threadIdx.x >> 6, lane = threadIdx.x & 63;
    int qp = __builtin_amdgcn_readfirstlane(blockIdx.x * 4 + wid);
    int q0 = qp << 2;                         // 4 queries per wave, same batch
    int col = lane & 31, g = lane >> 5;
    int b = q0 >> 11, n0 = q0 & (NN - 1);

    // ---- A-fragment build: lane row = out-channel, slot k = in-channel ----
    // f0-3: w0k natural k-labels. f4-15: pi-permuted so prev layer's D-register
    // form IS the next B-fragment: slot(g2,j,fl) holds in-ch (j&3)+8*(j>>2)+16fl+4g2.
    for (int e = threadIdx.x; e < 1024; e += 256) {
        int f = e >> 6, l = e & 63;
        int c = l & 31, g2 = l >> 5;
        unsigned short u[8];
#pragma unroll
        for (int j = 0; j < 8; ++j) {
            float v;
            if (f < 4) {
                int rr = 16 * f + 8 * g2 + j;
                v = Wf[(64 + rr) * 32 + c] + Wf[(128 + rr) * 32 + c];
            } else {
                int fl = f & 1;
                int rr = 4 * g2 + (j & 3) + 8 * ((j >> 2) + 2 * fl);
                if (f < 6)       v = W1[rr * 32 + c];
                else if (f < 8)  v = W2[rr * 32 + c];
                else if (f < 10) v = W2[(32 + rr) * 32 + c];
                else if (f < 12) v = Wl[rr * 32 + c];
                else if (f < 14) v = Wl[(32 + rr) * 32 + c];
                else             v = Wl[(64 + rr) * 32 + c];
            }
            u[j] = f2bf(v);
        }
        i32x4 pk = { (int)(u[0] | (u[1] << 16)), (int)(u[2] | (u[3] << 16)),
                     (int)(u[4] | (u[5] << 16)), (int)(u[6] | (u[7] << 16)) };
        lwf8[e] = __builtin_bit_cast(short8, pk);
    }

    // ---- bases from RAW weights (coalesced per half-wave), 8 independent FMA chains ----
    const float* xq0 = x + (size_t)q0 * DD;
    bool lo = lane < 32;
    int c0 = lane & 31;
    const float* pA1 = lo ? (Wf + c0) : (W1 + 32 * 32 + c0);
    const float* pA2 = lo ? (Wf + 128 * 32 + c0) : (W1 + 32 * 32 + c0);
    float sA = lo ? -1.0f : 0.0f;
    const float* pB1 = lo ? (W2 + 64 * 32 + c0) : (Wl + 96 * 32 + c0);
    float balA = lo ? bfv[c0] : b1[c0];
    float balB = lo ? b2[c0] : bl[c0];
    float aA[4] = {balA, balA, balA, balA};
    float aB[4] = {balB, balB, balB, balB};
#pragma unroll
    for (int j0 = 0; j0 < 16; ++j0) {
        float wa[4], wb[4];
#pragma unroll
        for (int jj = 0; jj < 4; ++jj) {
            int j = 4 * j0 + jj;
            wa[jj] = fmaf(sA, pA2[j * 32], pA1[j * 32]);
            wb[jj] = pB1[j * 32];
        }
#pragma unroll
        for (int t = 0; t < 4; ++t) {
            const float* xr = xq0 + t * DD + 4 * j0;
            float x0 = xr[0], x1 = xr[1], x2 = xr[2], x3 = xr[3];
            aA[t] = fmaf(x0, wa[0], aA[t]); aA[t] = fmaf(x1, wa[1], aA[t]);
            aA[t] = fmaf(x2, wa[2], aA[t]); aA[t] = fmaf(x3, wa[3], aA[t]);
            aB[t] = fmaf(x0, wb[0], aB[t]); aB[t] = fmaf(x1, wb[1], aB[t]);
            aB[t] = fmaf(x2, wb[2], aB[t]); aB[t] = fmaf(x3, wb[3], aB[t]);
        }
    }
#pragma unroll
    for (int t = 0; t < 4; ++t) {
        bss[wid][t * 128 + lane]      = aA[t];   // L0 (lo lanes) / L1 (hi lanes)
        bss[wid][t * 128 + 64 + lane] = aB[t];   // L2 / L3
    }

    // ---- shared-chunk ball query (exact reference arithmetic) ----
    const float* pb = pos + (size_t)b * NN * 3;
    float qxv[4], qyv[4], qzv[4], sq4[4];
#pragma unroll
    for (int t = 0; t < 4; ++t) {
        int n = n0 + t;
        qxv[t] = pb[3 * n]; qyv[t] = pb[3 * n + 1]; qzv[t] = pb[3 * n + 2];
        sq4[t] = __fadd_rn(__fadd_rn(__fmul_rn(qxv[t], qxv[t]), __fmul_rn(qyv[t], qyv[t])),
                           __fmul_rn(qzv[t], qzv[t]));
    }
    int cnt[4] = {0, 0, 0, 0};
    unsigned long long ltmask = (1ULL << lane) - 1ULL;
    for (int m0 = 0; m0 < NN; m0 += 64) {
        if (cnt[0] >= KK && cnt[1] >= KK && cnt[2] >= KK && cnt[3] >= KK) break;
        int m = m0 + lane;
        float mx3 = pb[3 * m], my3 = pb[3 * m + 1], mz3 = pb[3 * m + 2];
        float sqm = __fadd_rn(__fadd_rn(__fmul_rn(mx3, mx3), __fmul_rn(my3, my3)), __fmul_rn(mz3, mz3));
#pragma unroll
        for (int t = 0; t < 4; ++t) {
            if (cnt[t] < KK) {
                float dot = __fadd_rn(__fadd_rn(__fmul_rn(qxv[t], mx3), __fmul_rn(qyv[t], my3)),
                                      __fmul_rn(qzv[t], mz3));
                float d2 = __fsub_rn(__fadd_rn(sq4[t], sqm), __fmul_rn(2.0f, dot));
                bool hit = d2 < R2C;
                unsigned long long mask = __ballot(hit);
                if (hit) {
                    int p = cnt[t] + (int)__popcll(mask & ltmask);
                    if (p < KK) nbrs[wid][t][p] = m;
                }
                cnt[t] = __builtin_amdgcn_readfirstlane(cnt[t] + (int)__popcll(mask));
            }
        }
    }
    int nbn[4];
#pragma unroll
    for (int t = 0; t < 4; ++t) nbn[t] = nbrs[wid][t][col < cnt[t] ? col : 0];

    // ---- gather neighbor rows (B-frags: lane col = neighbor, slots = features) ----
    short8 xk[4][4];
#pragma unroll
    for (int t = 0; t < 4; ++t) {
        const float* xrow = x + (size_t)(b * NN + nbn[t]) * DD + g * 8;
#pragma unroll
        for (int kf = 0; kf < 4; ++kf) xk[t][kf] = cvt8(xrow + kf * 16);
    }

    __syncthreads();     // lwf8 ready
    const float* bp = bss[wid];

    auto bias_init = [&](f32x16& acc, int t, int L) {
#pragma unroll
        for (int m = 0; m < 4; ++m) {
            float4 r = *(const float4*)(bp + t * 128 + L * 32 + 8 * m + 4 * g);
            acc[4 * m] = r.x; acc[4 * m + 1] = r.y; acc[4 * m + 2] = r.z; acc[4 * m + 3] = r.w;
        }
    };
    auto post_pack = [&](const f32x16& a, int* d) {      // relu + pack: D-form -> next B-frag dwords
#pragma unroll
        for (int i = 0; i < 8; ++i)
            d[i] = cvtpk(fmaxf(a[2 * i], 0.0f), fmaxf(a[2 * i + 1], 0.0f));
    };
    // max over neighbors for packed non-negative bf16 (relu layers) -> out  [destroys d]
    auto maxstore_pk = [&](int* d, float* orow, int off) {
#pragma unroll
        for (int ms = 1; ms < 32; ms <<= 1) {
#pragma unroll
            for (int i = 0; i < 8; ++i) d[i] = pkmax(d[i], __shfl_xor(d[i], ms, 32));
        }
        int s = lane & 7;
        int sel = s == 0 ? d[0] : s == 1 ? d[1] : s == 2 ? d[2] : s == 3 ? d[3]
                : s == 4 ? d[4] : s == 5 ? d[5] : s == 6 ? d[6] : d[7];
        if (col < 8) {
            int c = ((2 * s) & 3) + 8 * (s >> 1) + 4 * g;
            float2 v = make_float2(__int_as_float(sel << 16),
                                   __int_as_float(sel & (int)0xFFFF0000));
            *(float2*)(orow + off + c) = v;
        }
    };
    // f32 max over neighbors for L3 (signed values)
    auto maxstore_f32 = [&](f32x16& a, float* orow) {
#pragma unroll
        for (int ms = 1; ms < 32; ms <<= 1) {
#pragma unroll
            for (int p = 0; p < 16; ++p) a[p] = fmaxf(a[p], __shfl_xor(a[p], ms, 32));
        }
        if (col < 8) {
            int c = ((2 * col) & 3) + 8 * (col >> 1) + 4 * g;
            float v0 = sel16(a, 2 * col);
            float v1 = sel16(a, 2 * col + 1);
            *(float2*)(orow + c) = make_float2(v0, v1);
        }
    };

#define WLD(f) lwf8[(f) * 64 + lane]
    // Pair-staggered, eager-accumulation pipeline. Per pair: 2x16 MFMAs,
    // h fragments die immediately after their consumers + maxstore.
    int ha[8], hb[8];
    f32x16 T0, T1, P01, P02, P03, P11, P12, P13;

#define PAIR_PHASE(TA, TB)                                                              \
    {                                                                                   \
        float* oA = out + (size_t)(q0 + (TA)) * 192;                                    \
        float* oB = out + (size_t)(q0 + (TB)) * 192;                                    \
        bias_init(T0, (TA), 0); bias_init(T1, (TB), 0);                                 \
        T0 = MF(WLD(0), xk[TA][0], T0); T1 = MF(WLD(0), xk[TB][0], T1);                 \
        T0 = MF(WLD(1), xk[TA][1], T0); T1 = MF(WLD(1), xk[TB][1], T1);                 \
        T0 = MF(WLD(2), xk[TA][2], T0); T1 = MF(WLD(2), xk[TB][2], T1);                 \
        T0 = MF(WLD(3), xk[TA][3], T0); T1 = MF(WLD(3), xk[TB][3], T1);                 \
        post_pack(T0, ha); post_pack(T1, hb);                                           \
        bias_init(P01, (TA), 1); bias_init(P11, (TB), 1);                               \
        bias_init(P02, (TA), 2); bias_init(P12, (TB), 2);                               \
        bias_init(P03, (TA), 3); bias_init(P13, (TB), 3);                               \
        P01 = MF(WLD(4),  fr(ha), P01); P11 = MF(WLD(4),  fr(hb), P11);                 \
        P01 = MF(WLD(5),  fr(ha + 4), P01); P11 = MF(WLD(5),  fr(hb + 4), P11);         \
        P02 = MF(WLD(8),  fr(ha), P02); P12 = MF(WLD(8),  fr(hb), P12);                 \
        P02 = MF(WLD(9),  fr(ha + 4), P02); P12 = MF(WLD(9),  fr(hb + 4), P12);         \
        P03 = MF(WLD(14), fr(ha), P03); P13 = MF(WLD(14), fr(hb), P13);                 \
        P03 = MF(WLD(15), fr(ha + 4), P03); P13 = MF(WLD(15), fr(hb + 4), P13);         \
        maxstore_pk(ha, oA, 96); maxstore_pk(hb, oB, 96);                               \
        post_pack(P01, ha); post_pack(P11, hb);          /* h1 */                       \
        P02 = MF(WLD(6),  fr(ha), P02); P12 = MF(WLD(6),  fr(hb), P12);                 \
        P02 = MF(WLD(7),  fr(ha + 4), P02); P12 = MF(WLD(7),  fr(hb + 4), P12);         \
        P03 = MF(WLD(12), fr(ha), P03); P13 = MF(WLD(12), fr(hb), P13);                 \
        P03 = MF(WLD(13), fr(ha + 4), P03); P13 = MF(WLD(13), fr(hb + 4), P13);         \
        maxstore_pk(ha, oA, 64); maxstore_pk(hb, oB, 64);                               \
        post_pack(P02, ha); post_pack(P12, hb);          /* h2 */                       \
        P03 = MF(WLD(10), fr(ha), P03); P13 = MF(WLD(10), fr(hb), P13);                 \
        P03 = MF(WLD(11), fr(ha + 4), P03); P13 = MF(WLD(11), fr(hb + 4), P13);         \
        maxstore_pk(ha, oA, 32); maxstore_pk(hb, oB, 32);                               \
        maxstore_f32(P03, oA); maxstore_f32(P13, oB);                                   \
    }

    PAIR_PHASE(0, 1)
    PAIR_PHASE(2, 3)
#undef PAIR_PHASE

    // ---- x passthrough ----
#pragma unroll
    for (int t = 0; t < 4; ++t)
        (out + (size_t)(q0 + t) * 192)[128 + lane] = xq0[t * DD + lane];
}

extern "C" void kernel_launch(void* const* d_in, const int* in_sizes, int n_in,
                              void* d_out, int out_size, void* d_ws, size_t ws_size,
                              hipStream_t stream) {
    const float* x   = (const float*)d_in[0];
    const float* pos = (const float*)d_in[1];
    const float* Wf  = (const float*)d_in[2];
    const float* bf  = (const float*)d_in[3];
    const float* W1  = (const float*)d_in[4];
    const float* b1  = (const float*)d_in[5];
    const float* W2  = (const float*)d_in[6];
    const float* b2  = (const float*)d_in[7];
    const float* Wl  = (const float*)d_in[8];
    const float* bl  = (const float*)d_in[9];
    float* out = (float*)d_out;

    hipLaunchKernelGGL(fused_kernel, dim3(512), dim3(256), 0, stream,
                       x, pos, Wf, bf, W1, b1, W2, b2, Wl, bl, out);
}